// Round 7
// baseline (242.554 us; speedup 1.0000x reference)
//
#include <hip/hip_runtime.h>
#include <hip/hip_bf16.h>

// Problem constants (B=8, T=2048, d_model=512, head_dim=64)
#define TT 2048
#define NB 8
#define DM 512
#define HD 64
static constexpr float SCALE = 0.04419417382415922f; // 512^-0.5

typedef short  s16x8 __attribute__((ext_vector_type(8)));   // 8 bf16 (4 VGPRs)
typedef float  f32x4 __attribute__((ext_vector_type(4)));

#define MFMA(a, b, c) __builtin_amdgcn_mfma_f32_16x16x32_bf16((a), (b), (c), 0, 0, 0)

// fp32 -> bf16 (RNE)
static __device__ inline unsigned short f2bf(float f) {
    unsigned int u = __float_as_uint(f);
    u += 0x7FFFu + ((u >> 16) & 1u);
    return (unsigned short)(u >> 16);
}

// ---------------------------------------------------------------- prep ----
// One launch: zero out (1024 blk, full 4 MB) + zero colsum (16 blk, full
// 64 KB — was 4 blk, a latent bug that only passed because 0xAA ~= -3e-13f)
// + convert W->bf16 (96 blk).
__global__ __launch_bounds__(256) void prep_kernel(
    const float* __restrict__ Wk, const float* __restrict__ Wq,
    const float* __restrict__ Wv, unsigned short* __restrict__ wbf,
    float* __restrict__ colsum, float* __restrict__ out) {
    const int bi = blockIdx.x, t = threadIdx.x;
    if (bi < 1024) {                     // zero out: 1,048,576 floats
        int i = (bi * 256 + t) * 4;
        *(float4*)(out + i) = make_float4(0.f, 0.f, 0.f, 0.f);
    } else if (bi < 1040) {              // zero colsum: 16,384 floats
        int i = ((bi - 1024) * 256 + t) * 4;
        *(float4*)(colsum + i) = make_float4(0.f, 0.f, 0.f, 0.f);
    } else {                             // convert W: 3*64*512 = 98,304 elems
        int g = ((bi - 1040) * 256 + t) * 4;
        int mat = g >> 15, off = g & 32767;
        const float* src = (mat == 0) ? Wk : (mat == 1) ? Wq : Wv;
        float4 f = *(const float4*)(src + off);
        wbf[g + 0] = f2bf(f.x); wbf[g + 1] = f2bf(f.y);
        wbf[g + 2] = f2bf(f.z); wbf[g + 3] = f2bf(f.w);
    }
}

// ----------------------------------------------------------------- qkv ----
// M=32 rows/block, N=192 (k|q|v), K=512. Grid 512 blocks.
// k,q written row-major [b*T+t][h]; v written TRANSPOSED vbT[b][h][t] so
// normpv can load PV B-fragments directly from global (no LDS transpose).
#define XS 72
__global__ __launch_bounds__(256) void qkv_kernel(
    const float* __restrict__ x, const unsigned short* __restrict__ wbf,
    unsigned short* __restrict__ kb, unsigned short* __restrict__ qb,
    unsigned short* __restrict__ vbT) {
    __shared__ unsigned short xs[32 * XS];
    const int i0 = blockIdx.x * 32;
    const int t = threadIdx.x;
    const int w = t >> 6, lane = t & 63;
    const int m15 = lane & 15, quad = lane >> 4;
    const int srow = t >> 3, c8 = (t & 7) * 8;    // staging: 32 rows x 64 cols
    f32x4 acc[2][3];
    for (int mt = 0; mt < 2; ++mt)
        for (int ct = 0; ct < 3; ++ct)
            acc[mt][ct] = (f32x4){0.f, 0.f, 0.f, 0.f};

    for (int kc = 0; kc < DM; kc += 64) {
        __syncthreads();
        {
            const float* gp = x + (size_t)(i0 + srow) * DM + kc + c8;
            float4 f0 = *(const float4*)gp;
            float4 f1 = *(const float4*)(gp + 4);
            s16x8 h;
            h[0] = (short)f2bf(f0.x); h[1] = (short)f2bf(f0.y);
            h[2] = (short)f2bf(f0.z); h[3] = (short)f2bf(f0.w);
            h[4] = (short)f2bf(f1.x); h[5] = (short)f2bf(f1.y);
            h[6] = (short)f2bf(f1.z); h[7] = (short)f2bf(f1.w);
            *(s16x8*)(xs + srow * XS + c8) = h;
        }
        __syncthreads();
        for (int ks = 0; ks < 2; ++ks) {
            s16x8 a[2];
            for (int mt = 0; mt < 2; ++mt)
                a[mt] = *(const s16x8*)(xs + (mt * 16 + m15) * XS + ks * 32 + quad * 8);
            for (int ct = 0; ct < 3; ++ct) {
                s16x8 bfr = *(const s16x8*)(wbf +
                    (size_t)((w * 3 + ct) * 16 + m15) * DM + kc + ks * 32 + quad * 8);
                acc[0][ct] = MFMA(a[0], bfr, acc[0][ct]);
                acc[1][ct] = MFMA(a[1], bfr, acc[1][ct]);
            }
        }
    }
    for (int mt = 0; mt < 2; ++mt)
        for (int ct = 0; ct < 3; ++ct) {
            int tile16 = w * 3 + ct;
            int col = (tile16 & 3) * 16 + m15;
            if (tile16 < 8) {            // k or q: row-major
                unsigned short* outp = (tile16 < 4) ? kb : qb;
                for (int r = 0; r < 4; ++r) {
                    int grow = i0 + mt * 16 + quad * 4 + r;
                    outp[(size_t)grow * HD + col] = f2bf(acc[mt][ct][r]);
                }
            } else {                     // v: transposed vbT[b][h][t]
                for (int r = 0; r < 4; ++r) {
                    int grow = i0 + mt * 16 + quad * 4 + r;
                    int bb = grow >> 11, tt = grow & 2047;
                    vbT[((size_t)bb * HD + col) * TT + tt] = f2bf(acc[mt][ct][r]);
                }
            }
        }
}

// -------------------------------------------------------------- colsum ----
// colsum[b][j] = sum_{i>=j} exp(SCALE * q_i . k_j)  — no E materialization.
__global__ __launch_bounds__(256) void colsum_kernel(
    const unsigned short* __restrict__ qb, const unsigned short* __restrict__ kb,
    float* __restrict__ colsum) {
    const int jt = blockIdx.x, ich = blockIdx.y, b = blockIdx.z;
    const int j0 = jt * 64;
    const int iend = (ich + 1) * 512;
    if (iend <= j0) return;
    const int t = threadIdx.x;
    const int w = t >> 6, lane = t & 63;
    const int m15 = lane & 15, quad = lane >> 4;
    s16x8 bk[4][2];
    for (int ct = 0; ct < 4; ++ct)
        for (int ks = 0; ks < 2; ++ks)
            bk[ct][ks] = *(const s16x8*)(kb +
                (size_t)(b * TT + j0 + ct * 16 + m15) * HD + ks * 32 + quad * 8);
    float csum[4] = {0.f, 0.f, 0.f, 0.f};
    const int istart = max(ich * 512, j0);
    for (int it = istart + w * 16; it < iend; it += 64) {   // 4 waves x 16 rows
        s16x8 aq[2];
        for (int ks = 0; ks < 2; ++ks)
            aq[ks] = *(const s16x8*)(qb +
                (size_t)(b * TT + it + m15) * HD + ks * 32 + quad * 8);
        for (int ct = 0; ct < 4; ++ct) {
            f32x4 s = (f32x4){0.f, 0.f, 0.f, 0.f};
            s = MFMA(aq[0], bk[ct][0], s);
            s = MFMA(aq[1], bk[ct][1], s);
            int gj = j0 + ct * 16 + m15;
            for (int r = 0; r < 4; ++r) {
                int gi = it + quad * 4 + r;
                float e = (gj <= gi) ? __expf(s[r] * SCALE) : 0.f;
                csum[ct] += e;
            }
        }
    }
    for (int ct = 0; ct < 4; ++ct) {
        csum[ct] += __shfl_xor(csum[ct], 16);
        csum[ct] += __shfl_xor(csum[ct], 32);
    }
    if (lane < 16)
        for (int ct = 0; ct < 4; ++ct)
            atomicAdd(&colsum[b * TT + j0 + ct * 16 + lane], csum[ct]);
}

// -------------------------------------------------------------- normpv ----
// Recompute S, normalize by colsum (divide inline), write attn exactly once,
// PV via MFMA with V B-frags loaded DIRECTLY from transposed global vbT.
// ZERO barriers: ps is wave-private (DS ops in-order within a wave).
#define PS 72
__global__ __launch_bounds__(256) void normpv_kernel(
    const unsigned short* __restrict__ qb, const unsigned short* __restrict__ kb,
    const unsigned short* __restrict__ vbT, const float* __restrict__ colsum,
    float* __restrict__ attn, float* __restrict__ out) {
    const int jch = blockIdx.x;          // j range [jch*512, +512)
    const int ti = blockIdx.y, b = blockIdx.z;
    const int i0 = ti * 64;
    const int jbase = jch * 512;
    float* abase = attn + (size_t)b * TT * TT;
    const int t = threadIdx.x;
    const float4 z = make_float4(0.f, 0.f, 0.f, 0.f);
    if (jbase > i0 + 63) {               // fully above diagonal: zeros only
        for (int e = 0; e < 32; ++e) {
            int f4 = e * 256 + t;
            int row = f4 >> 7, c4 = (f4 & 127) * 4;
            *(float4*)(abase + (size_t)(i0 + row) * TT + jbase + c4) = z;
        }
        return;
    }
    const int w = t >> 6, lane = t & 63;
    const int m15 = lane & 15, quad = lane >> 4;
    __shared__ unsigned short ps[4 * 16 * PS];  // per-wave P strips (private)
    unsigned short* psw = ps + w * 16 * PS;
    s16x8 aq[2];
    for (int ks = 0; ks < 2; ++ks)
        aq[ks] = *(const s16x8*)(qb +
            (size_t)(b * TT + i0 + w * 16 + m15) * HD + ks * 32 + quad * 8);
    f32x4 o[4];
    for (int ht = 0; ht < 4; ++ht) o[ht] = (f32x4){0.f, 0.f, 0.f, 0.f};
    const float* csb = colsum + b * TT;
    const unsigned short* vbb = vbT + (size_t)b * HD * TT;

    for (int jt = 0; jt < 8; ++jt) {
        const int j0 = jbase + jt * 64;
        if (j0 > i0 + 63) {              // above-diagonal tile: zeros (uniform)
            for (int e = 0; e < 4; ++e) {
                int f4 = e * 256 + t;
                int row = f4 >> 4, c4 = (f4 & 15) * 4;
                *(float4*)(abase + (size_t)(i0 + row) * TT + j0 + c4) = z;
            }
            continue;
        }
        // S = QK^T
        s16x8 bk[4][2];
        for (int ct = 0; ct < 4; ++ct)
            for (int ks = 0; ks < 2; ++ks)
                bk[ct][ks] = *(const s16x8*)(kb +
                    (size_t)(b * TT + j0 + ct * 16 + m15) * HD + ks * 32 + quad * 8);
        for (int ct = 0; ct < 4; ++ct) {
            f32x4 s = (f32x4){0.f, 0.f, 0.f, 0.f};
            s = MFMA(aq[0], bk[ct][0], s);
            s = MFMA(aq[1], bk[ct][1], s);
            int gj = j0 + ct * 16 + m15;
            float rc = 1.0f / csb[gj];
            for (int r = 0; r < 4; ++r) {
                int gi = i0 + w * 16 + quad * 4 + r;
                float e = (gj <= gi) ? __expf(s[r] * SCALE) : 0.f;
                float a = e * rc;
                abase[(size_t)gi * TT + gj] = a;
                psw[(quad * 4 + r) * PS + ct * 16 + m15] = f2bf(a);
            }
        }
        // PV: psw wave-private (no barrier); V B-frags direct from global
        for (int ks = 0; ks < 2; ++ks) {
            s16x8 ap = *(const s16x8*)(psw + m15 * PS + ks * 32 + quad * 8);
            for (int ht = 0; ht < 4; ++ht) {
                s16x8 bv = *(const s16x8*)(vbb +
                    (size_t)(ht * 16 + m15) * TT + j0 + ks * 32 + quad * 8);
                o[ht] = MFMA(ap, bv, o[ht]);
            }
        }
    }
    for (int ht = 0; ht < 4; ++ht)
        for (int r = 0; r < 4; ++r)
            atomicAdd(&out[(size_t)(b * TT + i0 + w * 16 + quad * 4 + r) * HD +
                           ht * 16 + m15], o[ht][r]);
}

// -------------------------------------------------------------- launch ----
extern "C" void kernel_launch(void* const* d_in, const int* in_sizes, int n_in,
                              void* d_out, int out_size, void* d_ws, size_t ws_size,
                              hipStream_t stream) {
    const float* x  = (const float*)d_in[0];
    const float* Wk = (const float*)d_in[1];
    const float* Wq = (const float*)d_in[2];
    const float* Wv = (const float*)d_in[3];
    // d_in[4] = mask sentinel (causal always on) — unused.

    float* out  = (float*)d_out;                       // [B,T,64]
    float* attn = out + (size_t)NB * TT * HD;          // [B,T,T]

    // workspace: k,q bf16 row-major; vbT bf16 transposed [B][HD][T];
    // colsum fp32; wbf bf16 weights
    unsigned short* kb  = (unsigned short*)d_ws;
    unsigned short* qb  = kb + (size_t)NB * TT * HD;
    unsigned short* vbT = qb + (size_t)NB * TT * HD;
    float* colsum = (float*)(vbT + (size_t)NB * TT * HD);
    unsigned short* wbf = (unsigned short*)(colsum + NB * TT);

    hipLaunchKernelGGL(prep_kernel, dim3(1136), dim3(256), 0, stream,
                       Wk, Wq, Wv, wbf, colsum, out);
    hipLaunchKernelGGL(qkv_kernel,  dim3(512), dim3(256), 0, stream,
                       x, wbf, kb, qb, vbT);
    hipLaunchKernelGGL(colsum_kernel, dim3(32, 4, 8), dim3(256), 0, stream,
                       qb, kb, colsum);
    hipLaunchKernelGGL(normpv_kernel, dim3(4, 32, 8), dim3(256), 0, stream,
                       qb, kb, vbT, colsum, attn, out);
}